// Round 16
// baseline (485.333 us; speedup 1.0000x reference)
//
#include <hip/hip_runtime.h>
#include <stdint.h>
#include <math.h>

typedef unsigned short u16;
typedef unsigned int   u32;
typedef unsigned long long u64;
typedef __attribute__((ext_vector_type(8))) short bf16x8;
typedef __attribute__((ext_vector_type(4))) float f32x4;

#define NB   4
#define NQ   4096
#define NPT  2048
#define DIM  256
#define KNN_ 16
#define LOG2E 1.44269504088896340736f

// ---------------- module-global scratch (no d_ws dependence) ----------------
__device__ int   g_knn[NB * NQ * KNN_];        // 1 MB
__device__ float g_qattn[NB * DIM];
__device__ float g_vglob[NB * DIM];
__device__ float g_attng[NB * DIM];            // pre-scaled by LOG2E
// fragment-ordered packed weights: [mat][ct][kt][lane][8] ; mats: Wd2,Wk,Wv,Wg1,Wg2
// Wg2 slot is pre-scaled by LOG2E (base-2 softmax).
__device__ u16   g_wpack[5 * DIM * DIM];       // 640 KB
__device__ u16   g_kmat[NB * NPT * DIM];       // 4 MB  K = points @ Wk^T
__device__ u16   g_vmat[NB * NPT * DIM];       // 4 MB  V = points @ Wv^T

__device__ __forceinline__ float bf2f(u16 u) {
    union { u32 i; float f; } v; v.i = ((u32)u) << 16; return v.f;
}
__device__ __forceinline__ u16 f2bf(float f) {
    union { float f; u32 i; } v; v.f = f;
    u32 u = v.i;
    return (u16)((u + 0x7FFFu + ((u >> 16) & 1u)) >> 16);
}
// fp32 -> bf16x8 fragment load (8 consecutive floats), optional scale
__device__ __forceinline__ bf16x8 ldfrag_s(const float* p, float sc) {
    float4 a = *(const float4*)p;
    float4 b = *(const float4*)(p + 4);
    bf16x8 r;
    r[0] = (short)f2bf(a.x * sc); r[1] = (short)f2bf(a.y * sc);
    r[2] = (short)f2bf(a.z * sc); r[3] = (short)f2bf(a.w * sc);
    r[4] = (short)f2bf(b.x * sc); r[5] = (short)f2bf(b.y * sc);
    r[6] = (short)f2bf(b.z * sc); r[7] = (short)f2bf(b.w * sc);
    return r;
}
__device__ __forceinline__ bf16x8 ldfrag(const float* p) { return ldfrag_s(p, 1.0f); }
// XOR-swizzled element address inside a [rows][256] bf16 LDS tile
__device__ __forceinline__ int swz(int r, int c) {
    return r * DIM + ((((c >> 3) ^ (r & 7))) << 3) + (c & 7);
}

// ---------------------------------------------------------------------------
// Repack the 5 hot weight matrices (fp32) into bf16 MFMA-fragment order.
// Wg2 (m==4) is pre-scaled by LOG2E for the base-2 softmax.
// ---------------------------------------------------------------------------
__global__ __launch_bounds__(256) void repack_kernel(
    const float* __restrict__ Wd2, const float* __restrict__ Wk,
    const float* __restrict__ Wv,  const float* __restrict__ Wg1,
    const float* __restrict__ Wg2)
{
    const float* srcs[5] = { Wd2, Wk, Wv, Wg1, Wg2 };
    const int m   = blockIdx.y;
    const int tid = blockIdx.x * 256 + threadIdx.x;   // 0..8191
    const int ct  = tid >> 9;
    const int kt  = (tid >> 6) & 7;
    const int q4  = (tid >> 4) & 3;
    const int l15 = tid & 15;
    const int row = ct * 16 + l15;
    const int col = (kt << 5) + (q4 << 3);
    const float sc = (m == 4) ? LOG2E : 1.0f;
    bf16x8 v = ldfrag_s(srcs[m] + (size_t)row * DIM + col, sc);
    *(bf16x8*)(g_wpack + m * DIM * DIM + (tid << 3)) = v;
}

// ---------------------------------------------------------------------------
// Proj: K or V (blockIdx.z) = points @ W^T once per point. 256 blocks.
// ---------------------------------------------------------------------------
__global__ __launch_bounds__(256) void proj_kernel(const float* __restrict__ points)
{
    __shared__ u16 bufP[64 * DIM];               // 32 KB swizzled points tile
    const int rb = blockIdx.x;                   // 0..31
    const int b  = blockIdx.y;                   // 0..3
    const int t  = threadIdx.x;
    const int r0 = rb * 64;
    for (int cc = t; cc < 64 * 32; cc += 256) {
        int r = cc >> 5, kc = cc & 31;
        bf16x8 v = ldfrag(points + ((size_t)b * NPT + r0 + r) * DIM + (kc << 3));
        *(bf16x8*)(bufP + r * DIM + ((kc ^ (r & 7)) << 3)) = v;
    }
    __syncthreads();
    const int w = t >> 6, lane = t & 63;
    const int rw = w << 4;
    const int q4 = lane >> 4, l15 = lane & 15;
    const int arow = rw + l15;
    bf16x8 afr[8];
    #pragma unroll
    for (int kt = 0; kt < 8; ++kt)
        afr[kt] = *(const bf16x8*)(bufP + arow * DIM + ((((kt << 2) + q4) ^ (arow & 7)) << 3));
    const u16* Wp = g_wpack + (blockIdx.z ? 2 : 1) * DIM * DIM;
    u16* Out     = blockIdx.z ? g_vmat : g_kmat;
    #pragma unroll 1
    for (int ct = 0; ct < 16; ++ct) {
        const int colg = (ct << 4) + l15;
        const int fbase = ((ct << 3) * 64 + lane) << 3;
        f32x4 acc = {0.f,0.f,0.f,0.f};
        #pragma unroll
        for (int kt = 0; kt < 8; ++kt) {
            bf16x8 bfr = *(const bf16x8*)(Wp + fbase + (kt << 9));
            acc = __builtin_amdgcn_mfma_f32_16x16x32_bf16(afr[kt], bfr, acc, 0, 0, 0);
        }
        #pragma unroll
        for (int reg = 0; reg < 4; ++reg) {
            const int rr = r0 + rw + (q4 << 2) + reg;
            Out[((size_t)b * NPT + rr) * DIM + colg] = f2bf(acc[reg]);
        }
    }
}

// ---------------------------------------------------------------------------
// Kernel A: exact 16-NN per query. f64 distances, index in low mantissa bits.
// ---------------------------------------------------------------------------
__global__ __launch_bounds__(256) void knn_kernel(const float* __restrict__ xyz_q,
                                                  const float* __restrict__ xyz)
{
    __shared__ float4 pts[NPT];                  // 32 KB
    const int b  = blockIdx.x >> 10;
    const int q0 = (blockIdx.x & 1023) << 2;
    const int t  = threadIdx.x;
    for (int i = t; i < NPT; i += 256) {
        const size_t base = ((size_t)b * NPT + i) * 3;
        pts[i] = make_float4(xyz[base + 0], xyz[base + 1], xyz[base + 2], 0.f);
    }
    __syncthreads();

    const int w = t >> 6, lane = t & 63;
    const int q = q0 + w;
    const size_t qb = ((size_t)b * NQ + q) * 3;
    const double qx = (double)xyz_q[qb + 0];
    const double qy = (double)xyz_q[qb + 1];
    const double qz = (double)xyz_q[qb + 2];

    u64 key[32];
    #pragma unroll
    for (int i = 0; i < 32; ++i) {
        const int n = (i << 6) + lane;
        float4 p = pts[n];
        double dx = qx - (double)p.x;
        double dy = qy - (double)p.y;
        double dz = qz - (double)p.z;
        double d2 = fma(dx, dx, fma(dy, dy, dz * dz));   // >= 0
        key[i] = (((u64)__double_as_longlong(d2)) & 0xFFFFFFFFFFFFF800ULL) | (u64)n;
    }
    u64 gmin[4];
    #pragma unroll
    for (int j = 0; j < 4; ++j) {
        u64 mn = key[8 * j];
        #pragma unroll
        for (int i = 1; i < 8; ++i) { u64 k2 = key[8 * j + i]; mn = k2 < mn ? k2 : mn; }
        gmin[j] = mn;
    }
    int* outp = g_knn + ((size_t)b * NQ + q) * KNN_;
    #pragma unroll 1
    for (int r = 0; r < KNN_; ++r) {
        u64 m01 = gmin[0] < gmin[1] ? gmin[0] : gmin[1];
        u64 m23 = gmin[2] < gmin[3] ? gmin[2] : gmin[3];
        u64 m   = m01 < m23 ? m01 : m23;
        #pragma unroll
        for (int off = 32; off >= 1; off >>= 1) {
            u64 o = __shfl_xor(m, off);
            m = o < m ? o : m;
        }
        if (lane == 0) outp[r] = (int)(m & 0x7FF);
        #pragma unroll
        for (int j = 0; j < 4; ++j) {
            if (gmin[j] == m) {
                u64 mn = ~0ULL;
                #pragma unroll
                for (int i = 0; i < 8; ++i) {
                    u64 k2 = key[8 * j + i];
                    k2 = (k2 == m) ? ~0ULL : k2;
                    key[8 * j + i] = k2;
                    mn = k2 < mn ? k2 : mn;
                }
                gmin[j] = mn;
            }
        }
    }
}

// ---------------------------------------------------------------------------
// Kernel B: per-batch q_attn, v_global, attn_g = MLP2(q_attn - k_global).
// attn_g is written PRE-SCALED by LOG2E (base-2 softmax).
// ---------------------------------------------------------------------------
__global__ __launch_bounds__(256) void gtok_kernel(const float* __restrict__ lat,
    const float* __restrict__ Wq,  const float* __restrict__ Wkg, const float* __restrict__ Wvg,
    const float* __restrict__ Wg1, const float* __restrict__ bg1,
    const float* __restrict__ Wg2, const float* __restrict__ bg2)
{
    const int b = blockIdx.x, t = threadIdx.x;
    __shared__ float latS[DIM], xS[DIM], hS[DIM];
    latS[t] = lat[(size_t)b * DIM + t];
    __syncthreads();
    float sq = 0.f, sk = 0.f, sv = 0.f;
    for (int i = 0; i < DIM; ++i) {
        float x = latS[i];
        sq += x * Wq[(size_t)t * DIM + i];
        sk += x * Wkg[(size_t)t * DIM + i];
        sv += x * Wvg[(size_t)t * DIM + i];
    }
    g_qattn[b * DIM + t] = sq;
    g_vglob[b * DIM + t] = sv;
    xS[t] = sq - sk;
    __syncthreads();
    float h = 0.f;
    for (int i = 0; i < DIM; ++i) h += xS[i] * Wg1[(size_t)t * DIM + i];
    h += bg1[t];
    hS[t] = fmaxf(h, 0.f);
    __syncthreads();
    float a = 0.f;
    for (int i = 0; i < DIM; ++i) a += hS[i] * Wg2[(size_t)t * DIM + i];
    a += bg2[t];
    g_attng[b * DIM + t] = a * LOG2E;
}

// ---------------------------------------------------------------------------
// Kernel C: fused attention — R15 + ONE change: raw s_barrier per ct in
// stages 2/3/4 so the block's 4 waves issue identical weight-fragment loads
// in lockstep (L1/MSHR sharing -> L2 read traffic /4). No memory-drain cost:
// raw s_barrier does not force vmcnt/lgkm flush; per-wave data deps private.
// ---------------------------------------------------------------------------
__global__ __launch_bounds__(256) void attn_kernel(
    const float* __restrict__ xyz_q, const float* __restrict__ xyz,
    const float* __restrict__ Wd1, const float* __restrict__ bd1,
    const float* __restrict__ bd2, const float* __restrict__ bg1,
    const float* __restrict__ bg2,
    float* __restrict__ out)
{
    __shared__ u16 bufA[64 * DIM];               // 32 KB, time-shared
    __shared__ int nbrS[64];
    __shared__ float wd1S[DIM * 4];              // (w0,w1,w2,bd1) fp32
    __shared__ float qaS[DIM], agS[DIM], vgS[DIM];
    __shared__ float bd2S[DIM], bg1S[DIM], bg2S[DIM];   // bg2S pre-scaled

    const int b  = blockIdx.x >> 10;
    const int q0 = (blockIdx.x & 1023) << 2;
    const int t  = threadIdx.x;

    // ---- stage 0: small shared data (the ONLY __syncthreads barrier)
    wd1S[t * 4 + 0] = Wd1[(size_t)t * 3 + 0];
    wd1S[t * 4 + 1] = Wd1[(size_t)t * 3 + 1];
    wd1S[t * 4 + 2] = Wd1[(size_t)t * 3 + 2];
    wd1S[t * 4 + 3] = bd1[t];
    bd2S[t] = bd2[t];
    bg1S[t] = bg1[t];
    bg2S[t] = bg2[t] * LOG2E;
    qaS[t] = g_qattn[b * DIM + t];
    agS[t] = g_attng[b * DIM + t];
    vgS[t] = g_vglob[b * DIM + t];
    if (t < 64) {
        int qq = q0 + (t >> 4);
        nbrS[t] = g_knn[((size_t)b * NQ + qq) * KNN_ + (t & 15)];
    }
    __syncthreads();

    const int w = t >> 6, lane = t & 63;
    const int q  = q0 + w;                       // one query per wave
    const int rw = w << 4;                       // this wave's 16 rows
    const int q4 = lane >> 4, l15 = lane & 15;
    const int arow = rw + l15;
    const int rgath = rw + (lane >> 2);          // gather row for this lane
    const int kcb   = lane & 3;                  // gather chunk base

    // packed-weight bases (fragment order): frag index = (ct*8+kt)*64 + lane
    const u16* WpD2 = g_wpack + 0 * DIM * DIM;
    const u16* WpG1 = g_wpack + 3 * DIM * DIM;
    const u16* WpG2 = g_wpack + 4 * DIM * DIM;

    // ---- stage V: gather this wave's 16 neighbor V rows into bufA, then
    //      lift to C-layout packed registers (raw bf16 bits, no conversion).
    {
        const size_t vb = ((size_t)b * NPT + nbrS[rgath]) * DIM;
        #pragma unroll
        for (int ci = 0; ci < 8; ++ci) {
            const int kc = kcb + (ci << 2);
            *(bf16x8*)(bufA + rgath * DIM + ((kc ^ (rgath & 7)) << 3)) =
                *(const bf16x8*)(g_vmat + vb + (kc << 3));
        }
    }
    u32 vp[32];                                   // V (later V+pos), C-layout
    {
        const int r0v = rw + (q4 << 2);
        #pragma unroll
        for (int ct = 0; ct < 16; ++ct) {
            const int colg = (ct << 4) + l15;
            vp[(ct << 1) + 0] = (u32)bufA[swz(r0v + 0, colg)]
                              | ((u32)bufA[swz(r0v + 1, colg)] << 16);
            vp[(ct << 1) + 1] = (u32)bufA[swz(r0v + 2, colg)]
                              | ((u32)bufA[swz(r0v + 3, colg)] << 16);
        }
    }

    // ---- stage 1: h1 = relu(d @ Wd1^T + bd1) -> bufA (over consumed V;
    //      in-order DS pipe: all lanes' V reads precede these writes)
    {
        const int n = nbrS[rgath];
        const size_t nb3 = ((size_t)b * NPT + n) * 3;
        const size_t qb3 = ((size_t)b * NQ  + q) * 3;
        const float dx = xyz_q[qb3 + 0] - xyz[nb3 + 0];
        const float dy = xyz_q[qb3 + 1] - xyz[nb3 + 1];
        const float dz = xyz_q[qb3 + 2] - xyz[nb3 + 2];
        #pragma unroll
        for (int ci = 0; ci < 8; ++ci) {
            const int kc = kcb + (ci << 2);
            u32 hw[4];
            #pragma unroll
            for (int pp = 0; pp < 4; ++pp) {
                const int c = (kc << 3) + pp * 2;
                const float* wv0 = wd1S + (size_t)c * 4;
                const float* wv1 = wd1S + (size_t)(c + 1) * 4;
                float h0 = wv0[0] * dx + wv0[1] * dy + wv0[2] * dz + wv0[3];
                float h1 = wv1[0] * dx + wv1[1] * dy + wv1[2] * dz + wv1[3];
                hw[pp] = (u32)f2bf(fmaxf(h0, 0.f)) | ((u32)f2bf(fmaxf(h1, 0.f)) << 16);
            }
            *(uint4*)(bufA + rgath * DIM + ((kc ^ (rgath & 7)) << 3)) = make_uint4(hw[0], hw[1], hw[2], hw[3]);
        }
    }

    // h1 fragments from LDS (consumes bufA h1)
    bf16x8 afrA[8];
    #pragma unroll
    for (int kt = 0; kt < 8; ++kt)
        afrA[kt] = *(const bf16x8*)(bufA + arow * DIM + ((((kt << 2) + q4) ^ (arow & 7)) << 3));

    // ---- stage K: gather precomputed K rows into bufA (over consumed h1)
    {
        const size_t kb = ((size_t)b * NPT + nbrS[rgath]) * DIM;
        #pragma unroll
        for (int ci = 0; ci < 8; ++ci) {
            const int kc = kcb + (ci << 2);
            *(bf16x8*)(bufA + rgath * DIM + ((kc ^ (rgath & 7)) << 3)) =
                *(const bf16x8*)(g_kmat + kb + (kc << 3));
        }
    }

    // ---- stage 2: pos = h1@Wd2^T + bd2; attn_in = (qa-K)+pos -> bufA;
    //      vp := bf16(V + pos) in-register. Lockstep per ct for L1 sharing.
    #pragma unroll 1
    for (int ct = 0; ct < 16; ++ct) {
        __builtin_amdgcn_s_barrier();
        const int colg = (ct << 4) + l15;
        const int fbase = ((ct << 3) * 64 + lane) << 3;   // + kt*512 per kt
        f32x4 aP = {0.f,0.f,0.f,0.f};
        #pragma unroll
        for (int kt = 0; kt < 8; ++kt) {
            bf16x8 bfrD = *(const bf16x8*)(WpD2 + fbase + (kt << 9));
            aP = __builtin_amdgcn_mfma_f32_16x16x32_bf16(afrA[kt], bfrD, aP, 0, 0, 0);
        }
        const float bb = bd2S[colg];
        const float qa = qaS[colg];
        const u32 p01 = vp[(ct << 1) + 0];
        const u32 p23 = vp[(ct << 1) + 1];
        u16 nb[4];
        #pragma unroll
        for (int reg = 0; reg < 4; ++reg) {
            const int ad = swz(rw + (q4 << 2) + reg, colg);
            const float pv = aP[reg] + bb;
            const float kv = bf2f(bufA[ad]);
            bufA[ad] = f2bf((qa - kv) + pv);
            const u32 praw = (reg < 2) ? p01 : p23;
            const float vv = bf2f((u16)((reg & 1) ? (praw >> 16) : (praw & 0xFFFF)));
            nb[reg] = f2bf(vv + pv);
        }
        vp[(ct << 1) + 0] = (u32)nb[0] | ((u32)nb[1] << 16);
        vp[(ct << 1) + 1] = (u32)nb[2] | ((u32)nb[3] << 16);
    }

    // ---- stage 3: g1 = relu(attn_in@Wg1^T + bg1) -> bufA (bias in acc-init)
    #pragma unroll
    for (int kt = 0; kt < 8; ++kt)
        afrA[kt] = *(const bf16x8*)(bufA + arow * DIM + ((((kt << 2) + q4) ^ (arow & 7)) << 3));
    #pragma unroll 1
    for (int ct = 0; ct < 16; ++ct) {
        __builtin_amdgcn_s_barrier();
        const int colg = (ct << 4) + l15;
        const int fbase = ((ct << 3) * 64 + lane) << 3;
        const float bb = bg1S[colg];
        f32x4 acc = {bb, bb, bb, bb};
        #pragma unroll
        for (int kt = 0; kt < 8; ++kt) {
            bf16x8 bfr = *(const bf16x8*)(WpG1 + fbase + (kt << 9));
            acc = __builtin_amdgcn_mfma_f32_16x16x32_bf16(afrA[kt], bfr, acc, 0, 0, 0);
        }
        #pragma unroll
        for (int reg = 0; reg < 4; ++reg) {
            const int rr = rw + (q4 << 2) + reg;
            bufA[swz(rr, colg)] = f2bf(fmaxf(acc[reg], 0.f));
        }
    }

    // ---- stage 4: logits2 = g1@(LOG2E*Wg2)^T + LOG2E*bg2 (bias in acc-init);
    //               base-2 softmax over 16 nbrs + global; output.
    #pragma unroll
    for (int kt = 0; kt < 8; ++kt)
        afrA[kt] = *(const bf16x8*)(bufA + arow * DIM + ((((kt << 2) + q4) ^ (arow & 7)) << 3));
    const size_t outq = ((size_t)b * NQ + q) * DIM;
    #pragma unroll 1
    for (int ct = 0; ct < 16; ++ct) {
        __builtin_amdgcn_s_barrier();
        const int colg = (ct << 4) + l15;
        const int fbase = ((ct << 3) * 64 + lane) << 3;
        const float bb2 = bg2S[colg];
        f32x4 accL = {bb2, bb2, bb2, bb2};
        #pragma unroll
        for (int kt = 0; kt < 8; ++kt) {
            bf16x8 bfrG = *(const bf16x8*)(WpG2 + fbase + (kt << 9));
            accL = __builtin_amdgcn_mfma_f32_16x16x32_bf16(afrA[kt], bfrG, accL, 0, 0, 0);
        }
        const float l0 = accL[0];
        const float l1 = accL[1];
        const float l2 = accL[2];
        const float l3 = accL[3];
        const float gl = agS[colg];
        float mx = fmaxf(fmaxf(l0, l1), fmaxf(l2, l3));
        mx = fmaxf(mx, __shfl_xor(mx, 16));
        mx = fmaxf(mx, __shfl_xor(mx, 32));
        mx = fmaxf(mx, gl);
        const float e0 = exp2f(l0 - mx), e1 = exp2f(l1 - mx);
        const float e2 = exp2f(l2 - mx), e3 = exp2f(l3 - mx);
        float s = (e0 + e1) + (e2 + e3);
        s += __shfl_xor(s, 16);
        s += __shfl_xor(s, 32);
        const float eg  = exp2f(gl - mx);
        const float inv = 1.0f / (s + eg);
        const u32 p01 = vp[(ct << 1) + 0];
        const u32 p23 = vp[(ct << 1) + 1];
        float o = e0 * bf2f((u16)(p01 & 0xFFFF))
                + e1 * bf2f((u16)(p01 >> 16))
                + e2 * bf2f((u16)(p23 & 0xFFFF))
                + e3 * bf2f((u16)(p23 >> 16));
        o += __shfl_xor(o, 16);
        o += __shfl_xor(o, 32);
        o = (o + eg * vgS[colg]) * inv;
        if (lane < 16) out[outq + colg] = o;
    }
}

// ---------------------------------------------------------------------------
extern "C" void kernel_launch(void* const* d_in, const int* in_sizes, int n_in,
                              void* d_out, int out_size, void* d_ws, size_t ws_size,
                              hipStream_t stream)
{
    const float* xyz_q  = (const float*)d_in[0];
    const float* lat    = (const float*)d_in[1];
    const float* xyz    = (const float*)d_in[2];
    const float* points = (const float*)d_in[3];
    const float* Wd1 = (const float*)d_in[4];
    const float* bd1 = (const float*)d_in[5];
    const float* Wd2 = (const float*)d_in[6];
    const float* bd2 = (const float*)d_in[7];
    const float* Wg1 = (const float*)d_in[8];
    const float* bg1 = (const float*)d_in[9];
    const float* Wg2 = (const float*)d_in[10];
    const float* bg2 = (const float*)d_in[11];
    const float* Wkg = (const float*)d_in[12];
    const float* Wvg = (const float*)d_in[13];
    const float* Wq  = (const float*)d_in[14];
    const float* Wk  = (const float*)d_in[15];
    const float* Wv  = (const float*)d_in[16];

    repack_kernel<<<dim3(32, 5), 256, 0, stream>>>(Wd2, Wk, Wv, Wg1, Wg2);
    proj_kernel<<<dim3(32, 4, 2), 256, 0, stream>>>(points);
    knn_kernel<<<4096, 256, 0, stream>>>(xyz_q, xyz);
    gtok_kernel<<<4, 256, 0, stream>>>(lat, Wq, Wkg, Wvg, Wg1, bg1, Wg2, bg2);
    attn_kernel<<<4096, 256, 0, stream>>>(xyz_q, xyz,
                                          Wd1, bd1, bd2, bg1, bg2, (float*)d_out);
}

// Round 17
// 452.775 us; speedup vs baseline: 1.0719x; 1.0719x over previous
//
#include <hip/hip_runtime.h>
#include <stdint.h>
#include <math.h>

typedef unsigned short u16;
typedef unsigned int   u32;
typedef unsigned long long u64;
typedef __attribute__((ext_vector_type(8))) short bf16x8;
typedef __attribute__((ext_vector_type(4))) float f32x4;

#define NB   4
#define NQ   4096
#define NPT  2048
#define DIM  256
#define KNN_ 16
#define LOG2E 1.44269504088896340736f

// ---------------- module-global scratch (no d_ws dependence) ----------------
__device__ int   g_knn[NB * NQ * KNN_];        // 1 MB
__device__ float g_qattn[NB * DIM];
__device__ float g_vglob[NB * DIM];
__device__ float g_attng[NB * DIM];            // pre-scaled by LOG2E
// fragment-ordered packed weights: [mat][ct][kt][lane][8] ; mats: Wd2,Wk,Wv,Wg1,Wg2
// Wg2 slot is pre-scaled by LOG2E (base-2 softmax).
__device__ u16   g_wpack[5 * DIM * DIM];       // 640 KB
__device__ u16   g_kmat[NB * NPT * DIM];       // 4 MB  K = points @ Wk^T
__device__ u16   g_vmat[NB * NPT * DIM];       // 4 MB  V = points @ Wv^T

__device__ __forceinline__ float bf2f(u16 u) {
    union { u32 i; float f; } v; v.i = ((u32)u) << 16; return v.f;
}
__device__ __forceinline__ u16 f2bf(float f) {
    union { float f; u32 i; } v; v.f = f;
    u32 u = v.i;
    return (u16)((u + 0x7FFFu + ((u >> 16) & 1u)) >> 16);
}
// fp32 -> bf16x8 fragment load (8 consecutive floats), optional scale
__device__ __forceinline__ bf16x8 ldfrag_s(const float* p, float sc) {
    float4 a = *(const float4*)p;
    float4 b = *(const float4*)(p + 4);
    bf16x8 r;
    r[0] = (short)f2bf(a.x * sc); r[1] = (short)f2bf(a.y * sc);
    r[2] = (short)f2bf(a.z * sc); r[3] = (short)f2bf(a.w * sc);
    r[4] = (short)f2bf(b.x * sc); r[5] = (short)f2bf(b.y * sc);
    r[6] = (short)f2bf(b.z * sc); r[7] = (short)f2bf(b.w * sc);
    return r;
}
__device__ __forceinline__ bf16x8 ldfrag(const float* p) { return ldfrag_s(p, 1.0f); }
// XOR-swizzled element address inside a [rows][256] bf16 LDS tile
__device__ __forceinline__ int swz(int r, int c) {
    return r * DIM + ((((c >> 3) ^ (r & 7))) << 3) + (c & 7);
}

// ---------------------------------------------------------------------------
// Prelude: knn (blocks 0..4095) + repack (4096..4255) + gtok (4256..4259).
// The three tasks are mutually independent; fusing hides the small tasks
// under knn's 4096 VALU-bound blocks and removes two launch gaps.
// ---------------------------------------------------------------------------
__global__ __launch_bounds__(256) void prelude_kernel(
    const float* __restrict__ xyz_q, const float* __restrict__ xyz,
    const float* __restrict__ Wd2, const float* __restrict__ Wk,
    const float* __restrict__ Wv,  const float* __restrict__ Wg1,
    const float* __restrict__ Wg2,
    const float* __restrict__ lat,
    const float* __restrict__ Wq,  const float* __restrict__ Wkg,
    const float* __restrict__ Wvg,
    const float* __restrict__ bg1, const float* __restrict__ bg2)
{
    __shared__ float4 pts[NPT];                  // 32 KB (knn); aliased by gtok
    const int bid = blockIdx.x;
    const int t   = threadIdx.x;

    if (bid < 4096) {
        // ------------------------------ knn ------------------------------
        const int b  = bid >> 10;
        const int q0 = (bid & 1023) << 2;
        for (int i = t; i < NPT; i += 256) {
            const size_t base = ((size_t)b * NPT + i) * 3;
            pts[i] = make_float4(xyz[base + 0], xyz[base + 1], xyz[base + 2], 0.f);
        }
        __syncthreads();

        const int w = t >> 6, lane = t & 63;
        const int q = q0 + w;
        const size_t qb = ((size_t)b * NQ + q) * 3;
        const double qx = (double)xyz_q[qb + 0];
        const double qy = (double)xyz_q[qb + 1];
        const double qz = (double)xyz_q[qb + 2];

        u64 key[32];
        #pragma unroll
        for (int i = 0; i < 32; ++i) {
            const int n = (i << 6) + lane;
            float4 p = pts[n];
            double dx = qx - (double)p.x;
            double dy = qy - (double)p.y;
            double dz = qz - (double)p.z;
            double d2 = fma(dx, dx, fma(dy, dy, dz * dz));   // >= 0
            key[i] = (((u64)__double_as_longlong(d2)) & 0xFFFFFFFFFFFFF800ULL) | (u64)n;
        }
        u64 gmin[4];
        #pragma unroll
        for (int j = 0; j < 4; ++j) {
            u64 mn = key[8 * j];
            #pragma unroll
            for (int i = 1; i < 8; ++i) { u64 k2 = key[8 * j + i]; mn = k2 < mn ? k2 : mn; }
            gmin[j] = mn;
        }
        int* outp = g_knn + ((size_t)b * NQ + q) * KNN_;
        #pragma unroll 1
        for (int r = 0; r < KNN_; ++r) {
            u64 m01 = gmin[0] < gmin[1] ? gmin[0] : gmin[1];
            u64 m23 = gmin[2] < gmin[3] ? gmin[2] : gmin[3];
            u64 m   = m01 < m23 ? m01 : m23;
            #pragma unroll
            for (int off = 32; off >= 1; off >>= 1) {
                u64 o = __shfl_xor(m, off);
                m = o < m ? o : m;
            }
            if (lane == 0) outp[r] = (int)(m & 0x7FF);
            #pragma unroll
            for (int j = 0; j < 4; ++j) {
                if (gmin[j] == m) {
                    u64 mn = ~0ULL;
                    #pragma unroll
                    for (int i = 0; i < 8; ++i) {
                        u64 k2 = key[8 * j + i];
                        k2 = (k2 == m) ? ~0ULL : k2;
                        key[8 * j + i] = k2;
                        mn = k2 < mn ? k2 : mn;
                    }
                    gmin[j] = mn;
                }
            }
        }
    } else if (bid < 4256) {
        // ----------------------------- repack ----------------------------
        const float* srcs[5] = { Wd2, Wk, Wv, Wg1, Wg2 };
        const int rb  = bid - 4096;               // 0..159
        const int m   = rb >> 5;                  // 0..4
        const int tid = (rb & 31) * 256 + t;      // 0..8191
        const int ct  = tid >> 9;
        const int kt  = (tid >> 6) & 7;
        const int q4  = (tid >> 4) & 3;
        const int l15 = tid & 15;
        const int row = ct * 16 + l15;
        const int col = (kt << 5) + (q4 << 3);
        const float sc = (m == 4) ? LOG2E : 1.0f;
        bf16x8 v = ldfrag_s(srcs[m] + (size_t)row * DIM + col, sc);
        *(bf16x8*)(g_wpack + m * DIM * DIM + (tid << 3)) = v;
    } else {
        // ------------------------------ gtok ------------------------------
        const int b = bid - 4256;                 // 0..3
        float* latS = (float*)pts;                // alias knn LDS
        float* xS   = latS + DIM;
        float* hS   = latS + 2 * DIM;
        latS[t] = lat[(size_t)b * DIM + t];
        __syncthreads();
        float sq = 0.f, sk = 0.f, sv = 0.f;
        for (int i = 0; i < DIM; ++i) {
            float x = latS[i];
            sq += x * Wq[(size_t)t * DIM + i];
            sk += x * Wkg[(size_t)t * DIM + i];
            sv += x * Wvg[(size_t)t * DIM + i];
        }
        g_qattn[b * DIM + t] = sq;
        g_vglob[b * DIM + t] = sv;
        xS[t] = sq - sk;
        __syncthreads();
        float h = 0.f;
        for (int i = 0; i < DIM; ++i) h += xS[i] * Wg1[(size_t)t * DIM + i];
        h += bg1[t];
        hS[t] = fmaxf(h, 0.f);
        __syncthreads();
        float a = 0.f;
        for (int i = 0; i < DIM; ++i) a += hS[i] * Wg2[(size_t)t * DIM + i];
        a += bg2[t];
        g_attng[b * DIM + t] = a * LOG2E;
    }
}

// ---------------------------------------------------------------------------
// Proj: K or V (blockIdx.z) = points @ W^T once per point. 256 blocks.
// ---------------------------------------------------------------------------
__global__ __launch_bounds__(256) void proj_kernel(const float* __restrict__ points)
{
    __shared__ u16 bufP[64 * DIM];               // 32 KB swizzled points tile
    const int rb = blockIdx.x;                   // 0..31
    const int b  = blockIdx.y;                   // 0..3
    const int t  = threadIdx.x;
    const int r0 = rb * 64;
    for (int cc = t; cc < 64 * 32; cc += 256) {
        int r = cc >> 5, kc = cc & 31;
        bf16x8 v = ldfrag(points + ((size_t)b * NPT + r0 + r) * DIM + (kc << 3));
        *(bf16x8*)(bufP + r * DIM + ((kc ^ (r & 7)) << 3)) = v;
    }
    __syncthreads();
    const int w = t >> 6, lane = t & 63;
    const int rw = w << 4;
    const int q4 = lane >> 4, l15 = lane & 15;
    const int arow = rw + l15;
    bf16x8 afr[8];
    #pragma unroll
    for (int kt = 0; kt < 8; ++kt)
        afr[kt] = *(const bf16x8*)(bufP + arow * DIM + ((((kt << 2) + q4) ^ (arow & 7)) << 3));
    const u16* Wp = g_wpack + (blockIdx.z ? 2 : 1) * DIM * DIM;
    u16* Out     = blockIdx.z ? g_vmat : g_kmat;
    #pragma unroll 1
    for (int ct = 0; ct < 16; ++ct) {
        const int colg = (ct << 4) + l15;
        const int fbase = ((ct << 3) * 64 + lane) << 3;
        f32x4 acc = {0.f,0.f,0.f,0.f};
        #pragma unroll
        for (int kt = 0; kt < 8; ++kt) {
            bf16x8 bfr = *(const bf16x8*)(Wp + fbase + (kt << 9));
            acc = __builtin_amdgcn_mfma_f32_16x16x32_bf16(afr[kt], bfr, acc, 0, 0, 0);
        }
        #pragma unroll
        for (int reg = 0; reg < 4; ++reg) {
            const int rr = r0 + rw + (q4 << 2) + reg;
            Out[((size_t)b * NPT + rr) * DIM + colg] = f2bf(acc[reg]);
        }
    }
}

// ---------------------------------------------------------------------------
// Kernel C: fused attention — exact R15 configuration (best measured:
// 277 us; acc-init bias + base-2 softmax; NO per-ct barriers).
// ---------------------------------------------------------------------------
__global__ __launch_bounds__(256) void attn_kernel(
    const float* __restrict__ xyz_q, const float* __restrict__ xyz,
    const float* __restrict__ Wd1, const float* __restrict__ bd1,
    const float* __restrict__ bd2, const float* __restrict__ bg1,
    const float* __restrict__ bg2,
    float* __restrict__ out)
{
    __shared__ u16 bufA[64 * DIM];               // 32 KB, time-shared
    __shared__ int nbrS[64];
    __shared__ float wd1S[DIM * 4];              // (w0,w1,w2,bd1) fp32
    __shared__ float qaS[DIM], agS[DIM], vgS[DIM];
    __shared__ float bd2S[DIM], bg1S[DIM], bg2S[DIM];   // bg2S pre-scaled

    const int b  = blockIdx.x >> 10;
    const int q0 = (blockIdx.x & 1023) << 2;
    const int t  = threadIdx.x;

    // ---- stage 0: small shared data (the ONLY barrier-protected stage)
    wd1S[t * 4 + 0] = Wd1[(size_t)t * 3 + 0];
    wd1S[t * 4 + 1] = Wd1[(size_t)t * 3 + 1];
    wd1S[t * 4 + 2] = Wd1[(size_t)t * 3 + 2];
    wd1S[t * 4 + 3] = bd1[t];
    bd2S[t] = bd2[t];
    bg1S[t] = bg1[t];
    bg2S[t] = bg2[t] * LOG2E;
    qaS[t] = g_qattn[b * DIM + t];
    agS[t] = g_attng[b * DIM + t];
    vgS[t] = g_vglob[b * DIM + t];
    if (t < 64) {
        int qq = q0 + (t >> 4);
        nbrS[t] = g_knn[((size_t)b * NQ + qq) * KNN_ + (t & 15)];
    }
    __syncthreads();

    const int w = t >> 6, lane = t & 63;
    const int q  = q0 + w;                       // one query per wave
    const int rw = w << 4;                       // this wave's 16 rows
    const int q4 = lane >> 4, l15 = lane & 15;
    const int arow = rw + l15;
    const int rgath = rw + (lane >> 2);          // gather row for this lane
    const int kcb   = lane & 3;                  // gather chunk base

    // packed-weight bases (fragment order): frag index = (ct*8+kt)*64 + lane
    const u16* WpD2 = g_wpack + 0 * DIM * DIM;
    const u16* WpG1 = g_wpack + 3 * DIM * DIM;
    const u16* WpG2 = g_wpack + 4 * DIM * DIM;

    // ---- stage V: gather this wave's 16 neighbor V rows into bufA, then
    //      lift to C-layout packed registers (raw bf16 bits, no conversion).
    {
        const size_t vb = ((size_t)b * NPT + nbrS[rgath]) * DIM;
        #pragma unroll
        for (int ci = 0; ci < 8; ++ci) {
            const int kc = kcb + (ci << 2);
            *(bf16x8*)(bufA + rgath * DIM + ((kc ^ (rgath & 7)) << 3)) =
                *(const bf16x8*)(g_vmat + vb + (kc << 3));
        }
    }
    u32 vp[32];                                   // V (later V+pos), C-layout
    {
        const int r0v = rw + (q4 << 2);
        #pragma unroll
        for (int ct = 0; ct < 16; ++ct) {
            const int colg = (ct << 4) + l15;
            vp[(ct << 1) + 0] = (u32)bufA[swz(r0v + 0, colg)]
                              | ((u32)bufA[swz(r0v + 1, colg)] << 16);
            vp[(ct << 1) + 1] = (u32)bufA[swz(r0v + 2, colg)]
                              | ((u32)bufA[swz(r0v + 3, colg)] << 16);
        }
    }

    // ---- stage 1: h1 = relu(d @ Wd1^T + bd1) -> bufA (over consumed V;
    //      in-order DS pipe: all lanes' V reads precede these writes)
    {
        const int n = nbrS[rgath];
        const size_t nb3 = ((size_t)b * NPT + n) * 3;
        const size_t qb3 = ((size_t)b * NQ  + q) * 3;
        const float dx = xyz_q[qb3 + 0] - xyz[nb3 + 0];
        const float dy = xyz_q[qb3 + 1] - xyz[nb3 + 1];
        const float dz = xyz_q[qb3 + 2] - xyz[nb3 + 2];
        #pragma unroll
        for (int ci = 0; ci < 8; ++ci) {
            const int kc = kcb + (ci << 2);
            u32 hw[4];
            #pragma unroll
            for (int pp = 0; pp < 4; ++pp) {
                const int c = (kc << 3) + pp * 2;
                const float* wv0 = wd1S + (size_t)c * 4;
                const float* wv1 = wd1S + (size_t)(c + 1) * 4;
                float h0 = wv0[0] * dx + wv0[1] * dy + wv0[2] * dz + wv0[3];
                float h1 = wv1[0] * dx + wv1[1] * dy + wv1[2] * dz + wv1[3];
                hw[pp] = (u32)f2bf(fmaxf(h0, 0.f)) | ((u32)f2bf(fmaxf(h1, 0.f)) << 16);
            }
            *(uint4*)(bufA + rgath * DIM + ((kc ^ (rgath & 7)) << 3)) = make_uint4(hw[0], hw[1], hw[2], hw[3]);
        }
    }

    // h1 fragments from LDS (consumes bufA h1)
    bf16x8 afrA[8];
    #pragma unroll
    for (int kt = 0; kt < 8; ++kt)
        afrA[kt] = *(const bf16x8*)(bufA + arow * DIM + ((((kt << 2) + q4) ^ (arow & 7)) << 3));

    // ---- stage K: gather precomputed K rows into bufA (over consumed h1)
    {
        const size_t kb = ((size_t)b * NPT + nbrS[rgath]) * DIM;
        #pragma unroll
        for (int ci = 0; ci < 8; ++ci) {
            const int kc = kcb + (ci << 2);
            *(bf16x8*)(bufA + rgath * DIM + ((kc ^ (rgath & 7)) << 3)) =
                *(const bf16x8*)(g_kmat + kb + (kc << 3));
        }
    }

    // ---- stage 2: pos = h1@Wd2^T + bd2; attn_in = (qa-K)+pos -> bufA;
    //      vp := bf16(V + pos) in-register.
    #pragma unroll 1
    for (int ct = 0; ct < 16; ++ct) {
        const int colg = (ct << 4) + l15;
        const int fbase = ((ct << 3) * 64 + lane) << 3;   // + kt*512 per kt
        f32x4 aP = {0.f,0.f,0.f,0.f};
        #pragma unroll
        for (int kt = 0; kt < 8; ++kt) {
            bf16x8 bfrD = *(const bf16x8*)(WpD2 + fbase + (kt << 9));
            aP = __builtin_amdgcn_mfma_f32_16x16x32_bf16(afrA[kt], bfrD, aP, 0, 0, 0);
        }
        const float bb = bd2S[colg];
        const float qa = qaS[colg];
        const u32 p01 = vp[(ct << 1) + 0];
        const u32 p23 = vp[(ct << 1) + 1];
        u16 nb[4];
        #pragma unroll
        for (int reg = 0; reg < 4; ++reg) {
            const int ad = swz(rw + (q4 << 2) + reg, colg);
            const float pv = aP[reg] + bb;
            const float kv = bf2f(bufA[ad]);
            bufA[ad] = f2bf((qa - kv) + pv);
            const u32 praw = (reg < 2) ? p01 : p23;
            const float vv = bf2f((u16)((reg & 1) ? (praw >> 16) : (praw & 0xFFFF)));
            nb[reg] = f2bf(vv + pv);
        }
        vp[(ct << 1) + 0] = (u32)nb[0] | ((u32)nb[1] << 16);
        vp[(ct << 1) + 1] = (u32)nb[2] | ((u32)nb[3] << 16);
    }

    // ---- stage 3: g1 = relu(attn_in@Wg1^T + bg1) -> bufA (bias in acc-init)
    #pragma unroll
    for (int kt = 0; kt < 8; ++kt)
        afrA[kt] = *(const bf16x8*)(bufA + arow * DIM + ((((kt << 2) + q4) ^ (arow & 7)) << 3));
    #pragma unroll 1
    for (int ct = 0; ct < 16; ++ct) {
        const int colg = (ct << 4) + l15;
        const int fbase = ((ct << 3) * 64 + lane) << 3;
        const float bb = bg1S[colg];
        f32x4 acc = {bb, bb, bb, bb};
        #pragma unroll
        for (int kt = 0; kt < 8; ++kt) {
            bf16x8 bfr = *(const bf16x8*)(WpG1 + fbase + (kt << 9));
            acc = __builtin_amdgcn_mfma_f32_16x16x32_bf16(afrA[kt], bfr, acc, 0, 0, 0);
        }
        #pragma unroll
        for (int reg = 0; reg < 4; ++reg) {
            const int rr = rw + (q4 << 2) + reg;
            bufA[swz(rr, colg)] = f2bf(fmaxf(acc[reg], 0.f));
        }
    }

    // ---- stage 4: logits2 = g1@(LOG2E*Wg2)^T + LOG2E*bg2 (bias in acc-init);
    //               base-2 softmax over 16 nbrs + global; output.
    #pragma unroll
    for (int kt = 0; kt < 8; ++kt)
        afrA[kt] = *(const bf16x8*)(bufA + arow * DIM + ((((kt << 2) + q4) ^ (arow & 7)) << 3));
    const size_t outq = ((size_t)b * NQ + q) * DIM;
    #pragma unroll 1
    for (int ct = 0; ct < 16; ++ct) {
        const int colg = (ct << 4) + l15;
        const int fbase = ((ct << 3) * 64 + lane) << 3;
        const float bb2 = bg2S[colg];
        f32x4 accL = {bb2, bb2, bb2, bb2};
        #pragma unroll
        for (int kt = 0; kt < 8; ++kt) {
            bf16x8 bfrG = *(const bf16x8*)(WpG2 + fbase + (kt << 9));
            accL = __builtin_amdgcn_mfma_f32_16x16x32_bf16(afrA[kt], bfrG, accL, 0, 0, 0);
        }
        const float l0 = accL[0];
        const float l1 = accL[1];
        const float l2 = accL[2];
        const float l3 = accL[3];
        const float gl = agS[colg];
        float mx = fmaxf(fmaxf(l0, l1), fmaxf(l2, l3));
        mx = fmaxf(mx, __shfl_xor(mx, 16));
        mx = fmaxf(mx, __shfl_xor(mx, 32));
        mx = fmaxf(mx, gl);
        const float e0 = exp2f(l0 - mx), e1 = exp2f(l1 - mx);
        const float e2 = exp2f(l2 - mx), e3 = exp2f(l3 - mx);
        float s = (e0 + e1) + (e2 + e3);
        s += __shfl_xor(s, 16);
        s += __shfl_xor(s, 32);
        const float eg  = exp2f(gl - mx);
        const float inv = 1.0f / (s + eg);
        const u32 p01 = vp[(ct << 1) + 0];
        const u32 p23 = vp[(ct << 1) + 1];
        float o = e0 * bf2f((u16)(p01 & 0xFFFF))
                + e1 * bf2f((u16)(p01 >> 16))
                + e2 * bf2f((u16)(p23 & 0xFFFF))
                + e3 * bf2f((u16)(p23 >> 16));
        o += __shfl_xor(o, 16);
        o += __shfl_xor(o, 32);
        o = (o + eg * vgS[colg]) * inv;
        if (lane < 16) out[outq + colg] = o;
    }
}

// ---------------------------------------------------------------------------
extern "C" void kernel_launch(void* const* d_in, const int* in_sizes, int n_in,
                              void* d_out, int out_size, void* d_ws, size_t ws_size,
                              hipStream_t stream)
{
    const float* xyz_q  = (const float*)d_in[0];
    const float* lat    = (const float*)d_in[1];
    const float* xyz    = (const float*)d_in[2];
    const float* points = (const float*)d_in[3];
    const float* Wd1 = (const float*)d_in[4];
    const float* bd1 = (const float*)d_in[5];
    const float* Wd2 = (const float*)d_in[6];
    const float* bd2 = (const float*)d_in[7];
    const float* Wg1 = (const float*)d_in[8];
    const float* bg1 = (const float*)d_in[9];
    const float* Wg2 = (const float*)d_in[10];
    const float* bg2 = (const float*)d_in[11];
    const float* Wkg = (const float*)d_in[12];
    const float* Wvg = (const float*)d_in[13];
    const float* Wq  = (const float*)d_in[14];
    const float* Wk  = (const float*)d_in[15];
    const float* Wv  = (const float*)d_in[16];

    prelude_kernel<<<4260, 256, 0, stream>>>(xyz_q, xyz, Wd2, Wk, Wv, Wg1, Wg2,
                                             lat, Wq, Wkg, Wvg, bg1, bg2);
    proj_kernel<<<dim3(32, 4, 2), 256, 0, stream>>>(points);
    attn_kernel<<<4096, 256, 0, stream>>>(xyz_q, xyz,
                                          Wd1, bd1, bd2, bg1, bg2, (float*)d_out);
}